// Round 8
// baseline (621.556 us; speedup 1.0000x reference)
//
#include <hip/hip_runtime.h>
#include <hip/hip_bf16.h>
#include <math.h>

#define NG 4
#define NN 50000
#define NE 800000
#define DD 64
#define CAP 64
#define NT 64             // nodes per block tile
#define NTILE 391         // tiles per (graph, half): 391*64 = 25024 >= 25000
#define NTG (2 * NTILE)   // tiles per graph = 782
#define RCAP 1536         // region capacity (Poisson mean 1024, 16 sigma)

typedef __attribute__((ext_vector_type(8))) short short8;
typedef __attribute__((ext_vector_type(4))) float float4v;

__device__ __forceinline__ unsigned short f2b(float f) {
    union { __hip_bfloat16 h; unsigned short u; } cv;
    cv.h = __float2bfloat16(f);
    return cv.u;
}
__device__ __forceinline__ float b2f(unsigned short u) {
    union { unsigned short u; __hip_bfloat16 h; } cv;
    cv.u = u;
    return __bfloat162float(cv.h);
}

// ---- init: detect int64 (bit0) + verify MFMA layout (bit1), one block ------
__global__ void init_kernel(const int* __restrict__ ei, int* __restrict__ flags) {
    __shared__ alignas(16) unsigned short A[16 * 32];
    __shared__ unsigned short B[32 * 16];
    int t = threadIdx.x;
    int any_nonzero = 0;
    for (int i = t; i < 128; i += 64) any_nonzero |= ei[2 * i + 1];
    unsigned long long nz = __ballot(any_nonzero != 0);
    int is64 = (nz == 0ULL) ? 1 : 0;
    for (int i = t; i < 512; i += 64) {
        int r = i >> 5, k = i & 31;
        A[i] = f2b((float)(((r * 5 + k * 3) & 31) - 15));
        int kk = i >> 4, c = i & 15;
        B[i] = f2b((float)(((kk * 7 + c * 11) & 31) - 15));
    }
    __syncthreads();
    short8 a = *(const short8*)&A[(t & 15) * 32 + (t >> 4) * 8];
    int c = t & 15, kb = (t >> 4) * 8;
    short8 b;
    for (int j = 0; j < 8; ++j) b[j] = (short)B[(kb + j) * 16 + c];
    float4v acc = {0.f, 0.f, 0.f, 0.f};
    acc = __builtin_amdgcn_mfma_f32_16x16x32_bf16(a, b, acc, 0, 0, 0);
    int ok = 1;
    for (int reg = 0; reg < 4; ++reg) {
        int row = (t >> 4) * 4 + reg;
        float ref = 0.f;
        for (int k = 0; k < 32; ++k)
            ref += (float)(((row * 5 + k * 3) & 31) - 15) *
                   (float)(((k * 7 + c * 11) & 31) - 15);
        if (acc[reg] != ref) ok = 0;
    }
    unsigned long long vote = __ballot(ok);
    if (t == 0) flags[0] = is64 | ((vote == ~0ULL) ? 2 : 0);
}

// nt (streaming) edge-index load
__device__ __forceinline__ int nt_idx(const int* __restrict__ ei, long pos, int is64) {
    return is64 ? __builtin_nontemporal_load(ei + 2 * pos)
                : __builtin_nontemporal_load(ei + pos);
}

// ---- partition: edges -> per-tile regions of packed (dst<<16 | src) --------
// Slot s = blockIdx&7 -> XCD s; graph s>>1, dst half s&1 (appends to any one
// region come from a single XCD -> head lines live in one L2). Appends are
// head-clustered: consecutive atomicAdd reservations give consecutive slots,
// so 64B lines fill within microseconds -> write amplification ~1
// (vs per-node bucket scatter whose heads advance too slowly: 151MB of
// write-backs in rounds 5/6).
__global__ void partition_kernel(const int* __restrict__ ei, const int* __restrict__ flags,
                                 int* __restrict__ bcnt, unsigned int* __restrict__ part) {
    const int CH = 8;
    int is64 = flags[0] & 1;
    int s = blockIdx.x & 7;
    int g = s >> 1;
    int lo = (s & 1) * (NN / 2), hi = lo + (NN / 2);
    int bsl = blockIdx.x >> 3;
    int nthreads = (gridDim.x >> 3) * blockDim.x;
    int tid = bsl * blockDim.x + threadIdx.x;
    long ebase = (long)g * 2 * NE;

    for (int e0 = tid; e0 < NE; e0 += nthreads * CH) {
        int dstv[CH], srcv[CH];
        bool ok[CH];
#pragma unroll
        for (int j = 0; j < CH; ++j) {
            int e = e0 + j * nthreads;
            bool inb = e < NE;
            int ec = inb ? e : NE - 1;
            int d = nt_idx(ei, ebase + NE + ec, is64);
            dstv[j] = d;
            ok[j] = inb && d >= lo && d < hi;
        }
#pragma unroll
        for (int j = 0; j < CH; ++j) {
            int e = e0 + j * nthreads;
            int ec = e < NE ? e : NE - 1;
            srcv[j] = ok[j] ? nt_idx(ei, ebase + ec, is64) : 0;
        }
        int posv[CH];
#pragma unroll
        for (int j = 0; j < CH; ++j)
            posv[j] = ok[j] ? atomicAdd(&bcnt[g * NTG + (dstv[j] >> 6)], 1) : RCAP;
#pragma unroll
        for (int j = 0; j < CH; ++j)
            if (posv[j] < RCAP)
                part[(long)(g * NTG + (dstv[j] >> 6)) * RCAP + posv[j]] =
                    ((unsigned int)dstv[j] << 16) | (unsigned int)srcv[j];
    }
}

// ---- convert x f32 -> bf16 -------------------------------------------------
__global__ void convert_kernel(const float* __restrict__ x, unsigned short* __restrict__ xb) {
    long total = (long)NG * NN * DD / 4;
    long stride = (long)gridDim.x * blockDim.x;
    const float4* src = (const float4*)x;
    unsigned long long* dst = (unsigned long long*)xb;
    for (long i = (long)blockIdx.x * blockDim.x + threadIdx.x; i < total; i += stride) {
        float4 v = src[i];
        unsigned long long p = (unsigned long long)f2b(v.x)
                             | ((unsigned long long)f2b(v.y) << 16)
                             | ((unsigned long long)f2b(v.z) << 32)
                             | ((unsigned long long)f2b(v.w) << 48);
        dst[i] = p;
    }
}

// ---- fused bin + gather + MFMA layer ----------------------------------------
// Block = 64-node tile. Preamble: read the tile's region (coalesced u32) and
// bin srcs into LDS (bucket rows live in sM's memory; a bucket row is dead
// exactly when its mean row is written -> zero extra LDS, occupancy stays 6).
// Then: wave w gathers bf16 means for rows 16w..16w+15, 16x mfma_16x16x32_bf16,
// ELU, direct register->global stores.
template <int LAYER>  // 0: out = h (bf16), 1: out = d_out (f32)
__launch_bounds__(256, 6)
__global__ void sage_mfma_kernel(const unsigned short* __restrict__ xin,
                                 const int* __restrict__ bcnt,
                                 const unsigned int* __restrict__ part,
                                 const float* __restrict__ Wl, const float* __restrict__ Wr,
                                 const float* __restrict__ bias, void* __restrict__ outp,
                                 const int* __restrict__ flags) {
    if (!(flags[0] & 2)) return;
    __shared__ alignas(16) unsigned short sWT[2 * DD * DD];  // [m][col][k^swz] bf16, 16KB
    __shared__ alignas(16) unsigned short sM[NT * DD];       // bucket, then means, 8KB
    __shared__ int cnt_lds[NT];

    int s = blockIdx.x & 7, tb = blockIdx.x >> 3;
    int g = s >> 1;
    int tile = (s & 1) * NTILE + tb;      // halves match partition slots
    int base = tile * NT;
    long gn0 = (long)g * NN;

    if (threadIdx.x < NT) cnt_lds[threadIdx.x] = 0;

    // stage W^T swizzled (conflict-free b128 writes)
    for (int i = threadIdx.x; i < 1024; i += 256) {
        int col = i & 63, ko = (i >> 6) & 7, m = i >> 9;
        const float* Wsrc = (m == 0 ? Wl : Wr) + (long)g * DD * DD;
        short8 t;
#pragma unroll
        for (int j = 0; j < 8; ++j)
            t[j] = (short)f2b(Wsrc[(ko * 8 + j) * DD + col]);
        *(short8*)&sWT[m * DD * DD + col * DD + ((ko * 8) ^ ((col & 7) << 3))] = t;
    }
    __syncthreads();

    // ---- bin this tile's region into LDS ----
    int rc = bcnt[g * NTG + tile];
    int rcount = rc < RCAP ? rc : RCAP;
    const unsigned int* reg = part + (long)(g * NTG + tile) * RCAP;
    for (int i = threadIdx.x; i < rcount; i += 256) {
        unsigned int p = reg[i];
        int dl = (p >> 16) & 63;
        int pos = atomicAdd(&cnt_lds[dl], 1);
        if (pos < CAP) sM[dl * DD + pos] = (unsigned short)(p & 0xffffu);
    }
    __syncthreads();

    int lane = threadIdx.x & 63;
    int w = threadIdx.x >> 6;

    // ---- gather phase: bf16 means for this wave's 16 rows ----
#pragma unroll 1
    for (int j = 0; j < 16; ++j) {
        int rl = w * 16 + j;
        int node = base + rl;
        int ne = cnt_lds[rl];
        int nuse = ne < CAP ? ne : CAP;
        int msrc = (int)sM[rl * DD + lane];   // bucket row (dead after this j)
        float mean = 0.f;
        if (node < NN) {
            float s0 = 0.f, s1 = 0.f, s2 = 0.f, s3 = 0.f;
            int e = 0;
            for (; e + 4 <= nuse; e += 4) {
                int a0 = __shfl(msrc, e), a1 = __shfl(msrc, e + 1);
                int a2 = __shfl(msrc, e + 2), a3 = __shfl(msrc, e + 3);
                s0 += b2f(xin[(gn0 + a0) * DD + lane]);
                s1 += b2f(xin[(gn0 + a1) * DD + lane]);
                s2 += b2f(xin[(gn0 + a2) * DD + lane]);
                s3 += b2f(xin[(gn0 + a3) * DD + lane]);
            }
            if (e < nuse) {
                int r = nuse - e;
                int a0 = __shfl(msrc, e);
                int a1 = __shfl(msrc, r > 1 ? e + 1 : e);
                int a2 = __shfl(msrc, r > 2 ? e + 2 : e);
                float v0 = b2f(xin[(gn0 + a0) * DD + lane]);
                float v1 = b2f(xin[(gn0 + a1) * DD + lane]);
                float v2 = b2f(xin[(gn0 + a2) * DD + lane]);
                s0 += v0;
                if (r > 1) s1 += v1;
                if (r > 2) s2 += v2;
            }
            mean = ((s0 + s1) + (s2 + s3)) / fmaxf((float)ne, 1.f);
        }
        sM[rl * DD + (lane ^ ((rl & 7) << 3))] = f2b(mean);  // own row, after read
    }

    // ---- MFMA phase (A-frags: direct b128 reads, conflict-free) ----
    int arow = w * 16 + (lane & 15);
    int kb = (lane >> 4) * 8;
    int selfrow = base + arow; if (selfrow > NN - 1) selfrow = NN - 1;
    short8 am[2], ax[2];
#pragma unroll
    for (int ss = 0; ss < 2; ++ss) {
        int f0 = (kb + 32 * ss) ^ ((arow & 7) << 3);
        am[ss] = *(const short8*)&sM[arow * DD + f0];
        ax[ss] = *(const short8*)&xin[(gn0 + selfrow) * DD + kb + 32 * ss];
    }

    float4v acc[4];
#pragma unroll
    for (int c = 0; c < 4; ++c) {
        float b = bias[g * DD + c * 16 + (lane & 15)];
        acc[c] = {b, b, b, b};
    }
#pragma unroll
    for (int c = 0; c < 4; ++c) {
        int col = c * 16 + (lane & 15);
        int cswz = (col & 7) << 3;
#pragma unroll
        for (int ss = 0; ss < 2; ++ss) {
            short8 bl = *(const short8*)&sWT[0 * DD * DD + col * DD + ((kb + 32 * ss) ^ cswz)];
            acc[c] = __builtin_amdgcn_mfma_f32_16x16x32_bf16(am[ss], bl, acc[c], 0, 0, 0);
        }
#pragma unroll
        for (int ss = 0; ss < 2; ++ss) {
            short8 br = *(const short8*)&sWT[1 * DD * DD + col * DD + ((kb + 32 * ss) ^ cswz)];
            acc[c] = __builtin_amdgcn_mfma_f32_16x16x32_bf16(ax[ss], br, acc[c], 0, 0, 0);
        }
    }

    int q = lane >> 4, cl = lane & 15;
#pragma unroll
    for (int c = 0; c < 4; ++c) {
        int col = c * 16 + cl;
#pragma unroll
        for (int r = 0; r < 4; ++r) {
            int grow = base + w * 16 + q * 4 + r;
            if (grow >= NN) continue;
            float v = acc[c][r];
            v = v > 0.f ? v : expm1f(v);
            if (LAYER == 0)
                ((unsigned short*)outp)[(gn0 + grow) * DD + col] = f2b(v);
            else
                ((float*)outp)[(gn0 + grow) * DD + col] = v;
        }
    }
}

// ---- fallback (shfl-matvec on binned tile), runs only if probe failed ------
template <int LAYER>
__global__ void fallback_kernel(const unsigned short* __restrict__ xin,
                                const int* __restrict__ bcnt,
                                const unsigned int* __restrict__ part,
                                const float* __restrict__ Wl, const float* __restrict__ Wr,
                                const float* __restrict__ bias, void* __restrict__ outp,
                                const int* __restrict__ flags) {
    if (flags[0] & 2) return;
    __shared__ float sWl[DD * DD];
    __shared__ float sWr[DD * DD];
    __shared__ float sb[DD];
    __shared__ unsigned short bk[NT * CAP];
    __shared__ int cnt_lds[NT];

    int s = blockIdx.x & 7, tb = blockIdx.x >> 3;
    int g = s >> 1;
    int tile = (s & 1) * NTILE + tb;
    int base = tile * NT;
    long gn0 = (long)g * NN;

    if (threadIdx.x < NT) cnt_lds[threadIdx.x] = 0;
    for (int i = threadIdx.x; i < DD * DD; i += blockDim.x) {
        sWl[i] = Wl[(long)g * DD * DD + i];
        sWr[i] = Wr[(long)g * DD * DD + i];
    }
    if (threadIdx.x < DD) sb[threadIdx.x] = bias[g * DD + threadIdx.x];
    __syncthreads();

    int rc = bcnt[g * NTG + tile];
    int rcount = rc < RCAP ? rc : RCAP;
    const unsigned int* reg = part + (long)(g * NTG + tile) * RCAP;
    for (int i = threadIdx.x; i < rcount; i += 256) {
        unsigned int p = reg[i];
        int dl = (p >> 16) & 63;
        int pos = atomicAdd(&cnt_lds[dl], 1);
        if (pos < CAP) bk[dl * CAP + pos] = (unsigned short)(p & 0xffffu);
    }
    __syncthreads();

    int lane = threadIdx.x & 63;
    int w = threadIdx.x >> 6;
    for (int j = 0; j < 16; ++j) {
        int rl = w * 16 + j;
        int node = base + rl;
        if (node >= NN) continue;
        long row = gn0 + node;
        int ne = cnt_lds[rl];
        int nuse = ne < CAP ? ne : CAP;
        int msrc = (int)bk[rl * CAP + lane];
        float sum = 0.f;
        for (int e = 0; e < nuse; ++e) {
            int a0 = __shfl(msrc, e);
            sum += b2f(xin[(gn0 + a0) * DD + lane]);
        }
        float mean = sum / fmaxf((float)ne, 1.f);
        float self = b2f(xin[row * DD + lane]);
        float acc = sb[lane];
#pragma unroll
        for (int k = 0; k < DD; ++k) {
            float mk = __shfl(mean, k);
            float xk = __shfl(self, k);
            acc += mk * sWl[k * DD + lane] + xk * sWr[k * DD + lane];
        }
        acc = acc > 0.f ? acc : expm1f(acc);
        if (LAYER == 0) ((unsigned short*)outp)[row * DD + lane] = f2b(acc);
        else            ((float*)outp)[row * DD + lane] = acc;
    }
}

extern "C" void kernel_launch(void* const* d_in, const int* in_sizes, int n_in,
                              void* d_out, int out_size, void* d_ws, size_t ws_size,
                              hipStream_t stream) {
    const float* x   = (const float*)d_in[0];
    const int*   ei  = (const int*)d_in[1];
    const float* Wl1 = (const float*)d_in[2];
    const float* Wr1 = (const float*)d_in[3];
    const float* b1  = (const float*)d_in[4];
    const float* Wl2 = (const float*)d_in[5];
    const float* Wr2 = (const float*)d_in[6];
    const float* b2  = (const float*)d_in[7];
    float* out = (float*)d_out;

    // ws: part u32[4*782*1536] (19.2MB) | bcnt i32[4*782] | h u16[4*50000*64]
    //     (25.6MB) | flags i32  -> ~44.8MB, under the 52MB proven budget
    unsigned int* part = (unsigned int*)d_ws;
    int* bcnt = (int*)(part + (size_t)NG * NTG * RCAP);
    unsigned short* h = (unsigned short*)(bcnt + (size_t)NG * NTG);
    int* flags = (int*)(h + (size_t)NG * NN * DD);
    // xb (x as bf16, 25.6MB) lives in d_out's first half; dead before layer 2
    unsigned short* xb = (unsigned short*)d_out;

    hipMemsetAsync(bcnt, 0, (size_t)NG * NTG * sizeof(int), stream);
    init_kernel<<<1, 64, 0, stream>>>(ei, flags);
    partition_kernel<<<2048, 256, 0, stream>>>(ei, flags, bcnt, part);
    convert_kernel<<<2048, 256, 0, stream>>>(x, xb);

    const int grid = NTILE * 8;  // 391 tb x 8 XCD slots
    // layer 1: xb -> h (bf16)
    sage_mfma_kernel<0><<<grid, 256, 0, stream>>>(xb, bcnt, part, Wl1, Wr1, b1, h, flags);
    fallback_kernel<0><<<grid, 256, 0, stream>>>(xb, bcnt, part, Wl1, Wr1, b1, h, flags);
    // layer 2: h -> out (f32)
    sage_mfma_kernel<1><<<grid, 256, 0, stream>>>(h, bcnt, part, Wl2, Wr2, b2, out, flags);
    fallback_kernel<1><<<grid, 256, 0, stream>>>(h, bcnt, part, Wl2, Wr2, b2, out, flags);
}

// Round 9
// 400.128 us; speedup vs baseline: 1.5534x; 1.5534x over previous
//
#include <hip/hip_runtime.h>
#include <hip/hip_bf16.h>
#include <math.h>

#define NG 4
#define NN 50000
#define NE 800000
#define DD 64
#define CAP 64
#define NT 64             // nodes per block tile
#define NTILE 391         // tiles per (graph, half): 391*64 = 25024 >= 25000
#define NTG (2 * NTILE)   // tiles per graph = 782
#define RCAP 1536         // region capacity (Poisson mean 1024, 16 sigma)
#define CPAD 16           // ints per region counter (one 64B line each)

typedef __attribute__((ext_vector_type(8))) short short8;
typedef __attribute__((ext_vector_type(4))) float float4v;

__device__ __forceinline__ unsigned short f2b(float f) {
    union { __hip_bfloat16 h; unsigned short u; } cv;
    cv.h = __float2bfloat16(f);
    return cv.u;
}
__device__ __forceinline__ float b2f(unsigned short u) {
    union { unsigned short u; __hip_bfloat16 h; } cv;
    cv.u = u;
    return __bfloat162float(cv.h);
}

// ---- init: detect int64 (bit0) + verify MFMA layout (bit1), one block ------
__global__ void init_kernel(const int* __restrict__ ei, int* __restrict__ flags) {
    __shared__ alignas(16) unsigned short A[16 * 32];
    __shared__ unsigned short B[32 * 16];
    int t = threadIdx.x;
    int any_nonzero = 0;
    for (int i = t; i < 128; i += 64) any_nonzero |= ei[2 * i + 1];
    unsigned long long nz = __ballot(any_nonzero != 0);
    int is64 = (nz == 0ULL) ? 1 : 0;
    for (int i = t; i < 512; i += 64) {
        int r = i >> 5, k = i & 31;
        A[i] = f2b((float)(((r * 5 + k * 3) & 31) - 15));
        int kk = i >> 4, c = i & 15;
        B[i] = f2b((float)(((kk * 7 + c * 11) & 31) - 15));
    }
    __syncthreads();
    short8 a = *(const short8*)&A[(t & 15) * 32 + (t >> 4) * 8];
    int c = t & 15, kb = (t >> 4) * 8;
    short8 b;
    for (int j = 0; j < 8; ++j) b[j] = (short)B[(kb + j) * 16 + c];
    float4v acc = {0.f, 0.f, 0.f, 0.f};
    acc = __builtin_amdgcn_mfma_f32_16x16x32_bf16(a, b, acc, 0, 0, 0);
    int ok = 1;
    for (int reg = 0; reg < 4; ++reg) {
        int row = (t >> 4) * 4 + reg;
        float ref = 0.f;
        for (int k = 0; k < 32; ++k)
            ref += (float)(((row * 5 + k * 3) & 31) - 15) *
                   (float)(((k * 7 + c * 11) & 31) - 15);
        if (acc[reg] != ref) ok = 0;
    }
    unsigned long long vote = __ballot(ok);
    if (t == 0) flags[0] = is64 | ((vote == ~0ULL) ? 2 : 0);
}

// nt (streaming) edge-index load
__device__ __forceinline__ int nt_idx(const int* __restrict__ ei, long pos, int is64) {
    return is64 ? __builtin_nontemporal_load(ei + 2 * pos)
                : __builtin_nontemporal_load(ei + pos);
}

// ---- partition: edges -> per-tile regions of packed (dst<<16 | src) --------
// Slot s = blockIdx&7 -> XCD s; graph s>>1, dst half s&1. Region = dst>>6.
// ROUND-9 CHANGE (H1 test): region counters padded to ONE PER 64B LINE
// (stride CPAD=16 ints). Round 8 packed 16 counters/line -> ~16K same-line
// atomic RMWs per line serialized in L2 (consistent with 340us, VALU 1.9%,
// writes 268 GB/s far under the ~1 TB/s random-write ceiling). Padding kills
// same-line aliasing; same-region collisions within a wave are ~5/64 lanes.
__global__ void partition_kernel(const int* __restrict__ ei, const int* __restrict__ flags,
                                 int* __restrict__ bcnt, unsigned int* __restrict__ part) {
    const int CH = 8;
    int is64 = flags[0] & 1;
    int s = blockIdx.x & 7;
    int g = s >> 1;
    int lo = (s & 1) * (NN / 2), hi = lo + (NN / 2);
    int bsl = blockIdx.x >> 3;
    int nthreads = (gridDim.x >> 3) * blockDim.x;
    int tid = bsl * blockDim.x + threadIdx.x;
    long ebase = (long)g * 2 * NE;

    for (int e0 = tid; e0 < NE; e0 += nthreads * CH) {
        int dstv[CH], srcv[CH];
        bool ok[CH];
#pragma unroll
        for (int j = 0; j < CH; ++j) {
            int e = e0 + j * nthreads;
            bool inb = e < NE;
            int ec = inb ? e : NE - 1;
            int d = nt_idx(ei, ebase + NE + ec, is64);
            dstv[j] = d;
            ok[j] = inb && d >= lo && d < hi;
        }
#pragma unroll
        for (int j = 0; j < CH; ++j) {
            int e = e0 + j * nthreads;
            int ec = e < NE ? e : NE - 1;
            srcv[j] = ok[j] ? nt_idx(ei, ebase + ec, is64) : 0;
        }
        int posv[CH];
#pragma unroll
        for (int j = 0; j < CH; ++j)
            posv[j] = ok[j] ? atomicAdd(&bcnt[(g * NTG + (dstv[j] >> 6)) * CPAD], 1) : RCAP;
#pragma unroll
        for (int j = 0; j < CH; ++j)
            if (posv[j] < RCAP)
                part[(long)(g * NTG + (dstv[j] >> 6)) * RCAP + posv[j]] =
                    ((unsigned int)dstv[j] << 16) | (unsigned int)srcv[j];
    }
}

// ---- convert x f32 -> bf16 -------------------------------------------------
__global__ void convert_kernel(const float* __restrict__ x, unsigned short* __restrict__ xb) {
    long total = (long)NG * NN * DD / 4;
    long stride = (long)gridDim.x * blockDim.x;
    const float4* src = (const float4*)x;
    unsigned long long* dst = (unsigned long long*)xb;
    for (long i = (long)blockIdx.x * blockDim.x + threadIdx.x; i < total; i += stride) {
        float4 v = src[i];
        unsigned long long p = (unsigned long long)f2b(v.x)
                             | ((unsigned long long)f2b(v.y) << 16)
                             | ((unsigned long long)f2b(v.z) << 32)
                             | ((unsigned long long)f2b(v.w) << 48);
        dst[i] = p;
    }
}

// ---- fused bin + gather + MFMA layer (unchanged from round 8) ---------------
template <int LAYER>  // 0: out = h (bf16), 1: out = d_out (f32)
__launch_bounds__(256, 6)
__global__ void sage_mfma_kernel(const unsigned short* __restrict__ xin,
                                 const int* __restrict__ bcnt,
                                 const unsigned int* __restrict__ part,
                                 const float* __restrict__ Wl, const float* __restrict__ Wr,
                                 const float* __restrict__ bias, void* __restrict__ outp,
                                 const int* __restrict__ flags) {
    if (!(flags[0] & 2)) return;
    __shared__ alignas(16) unsigned short sWT[2 * DD * DD];  // [m][col][k^swz] bf16, 16KB
    __shared__ alignas(16) unsigned short sM[NT * DD];       // bucket, then means, 8KB
    __shared__ int cnt_lds[NT];

    int s = blockIdx.x & 7, tb = blockIdx.x >> 3;
    int g = s >> 1;
    int tile = (s & 1) * NTILE + tb;      // halves match partition slots
    int base = tile * NT;
    long gn0 = (long)g * NN;

    if (threadIdx.x < NT) cnt_lds[threadIdx.x] = 0;

    // stage W^T swizzled (conflict-free b128 writes)
    for (int i = threadIdx.x; i < 1024; i += 256) {
        int col = i & 63, ko = (i >> 6) & 7, m = i >> 9;
        const float* Wsrc = (m == 0 ? Wl : Wr) + (long)g * DD * DD;
        short8 t;
#pragma unroll
        for (int j = 0; j < 8; ++j)
            t[j] = (short)f2b(Wsrc[(ko * 8 + j) * DD + col]);
        *(short8*)&sWT[m * DD * DD + col * DD + ((ko * 8) ^ ((col & 7) << 3))] = t;
    }
    __syncthreads();

    // ---- bin this tile's region into LDS ----
    int rc = bcnt[(g * NTG + tile) * CPAD];
    int rcount = rc < RCAP ? rc : RCAP;
    const unsigned int* reg = part + (long)(g * NTG + tile) * RCAP;
    for (int i = threadIdx.x; i < rcount; i += 256) {
        unsigned int p = reg[i];
        int dl = (p >> 16) & 63;
        int pos = atomicAdd(&cnt_lds[dl], 1);
        if (pos < CAP) sM[dl * DD + pos] = (unsigned short)(p & 0xffffu);
    }
    __syncthreads();

    int lane = threadIdx.x & 63;
    int w = threadIdx.x >> 6;

    // ---- gather phase: bf16 means for this wave's 16 rows ----
#pragma unroll 1
    for (int j = 0; j < 16; ++j) {
        int rl = w * 16 + j;
        int node = base + rl;
        int ne = cnt_lds[rl];
        int nuse = ne < CAP ? ne : CAP;
        int msrc = (int)sM[rl * DD + lane];   // bucket row (dead after this j)
        float mean = 0.f;
        if (node < NN) {
            float s0 = 0.f, s1 = 0.f, s2 = 0.f, s3 = 0.f;
            int e = 0;
            for (; e + 4 <= nuse; e += 4) {
                int a0 = __shfl(msrc, e), a1 = __shfl(msrc, e + 1);
                int a2 = __shfl(msrc, e + 2), a3 = __shfl(msrc, e + 3);
                s0 += b2f(xin[(gn0 + a0) * DD + lane]);
                s1 += b2f(xin[(gn0 + a1) * DD + lane]);
                s2 += b2f(xin[(gn0 + a2) * DD + lane]);
                s3 += b2f(xin[(gn0 + a3) * DD + lane]);
            }
            if (e < nuse) {
                int r = nuse - e;
                int a0 = __shfl(msrc, e);
                int a1 = __shfl(msrc, r > 1 ? e + 1 : e);
                int a2 = __shfl(msrc, r > 2 ? e + 2 : e);
                float v0 = b2f(xin[(gn0 + a0) * DD + lane]);
                float v1 = b2f(xin[(gn0 + a1) * DD + lane]);
                float v2 = b2f(xin[(gn0 + a2) * DD + lane]);
                s0 += v0;
                if (r > 1) s1 += v1;
                if (r > 2) s2 += v2;
            }
            mean = ((s0 + s1) + (s2 + s3)) / fmaxf((float)ne, 1.f);
        }
        sM[rl * DD + (lane ^ ((rl & 7) << 3))] = f2b(mean);  // own row, after read
    }

    // ---- MFMA phase (A-frags: direct b128 reads, conflict-free) ----
    int arow = w * 16 + (lane & 15);
    int kb = (lane >> 4) * 8;
    int selfrow = base + arow; if (selfrow > NN - 1) selfrow = NN - 1;
    short8 am[2], ax[2];
#pragma unroll
    for (int ss = 0; ss < 2; ++ss) {
        int f0 = (kb + 32 * ss) ^ ((arow & 7) << 3);
        am[ss] = *(const short8*)&sM[arow * DD + f0];
        ax[ss] = *(const short8*)&xin[(gn0 + selfrow) * DD + kb + 32 * ss];
    }

    float4v acc[4];
#pragma unroll
    for (int c = 0; c < 4; ++c) {
        float b = bias[g * DD + c * 16 + (lane & 15)];
        acc[c] = {b, b, b, b};
    }
#pragma unroll
    for (int c = 0; c < 4; ++c) {
        int col = c * 16 + (lane & 15);
        int cswz = (col & 7) << 3;
#pragma unroll
        for (int ss = 0; ss < 2; ++ss) {
            short8 bl = *(const short8*)&sWT[0 * DD * DD + col * DD + ((kb + 32 * ss) ^ cswz)];
            acc[c] = __builtin_amdgcn_mfma_f32_16x16x32_bf16(am[ss], bl, acc[c], 0, 0, 0);
        }
#pragma unroll
        for (int ss = 0; ss < 2; ++ss) {
            short8 br = *(const short8*)&sWT[1 * DD * DD + col * DD + ((kb + 32 * ss) ^ cswz)];
            acc[c] = __builtin_amdgcn_mfma_f32_16x16x32_bf16(ax[ss], br, acc[c], 0, 0, 0);
        }
    }

    int q = lane >> 4, cl = lane & 15;
#pragma unroll
    for (int c = 0; c < 4; ++c) {
        int col = c * 16 + cl;
#pragma unroll
        for (int r = 0; r < 4; ++r) {
            int grow = base + w * 16 + q * 4 + r;
            if (grow >= NN) continue;
            float v = acc[c][r];
            v = v > 0.f ? v : expm1f(v);
            if (LAYER == 0)
                ((unsigned short*)outp)[(gn0 + grow) * DD + col] = f2b(v);
            else
                ((float*)outp)[(gn0 + grow) * DD + col] = v;
        }
    }
}

// ---- fallback (shfl-matvec on binned tile), runs only if probe failed ------
template <int LAYER>
__global__ void fallback_kernel(const unsigned short* __restrict__ xin,
                                const int* __restrict__ bcnt,
                                const unsigned int* __restrict__ part,
                                const float* __restrict__ Wl, const float* __restrict__ Wr,
                                const float* __restrict__ bias, void* __restrict__ outp,
                                const int* __restrict__ flags) {
    if (flags[0] & 2) return;
    __shared__ float sWl[DD * DD];
    __shared__ float sWr[DD * DD];
    __shared__ float sb[DD];
    __shared__ unsigned short bk[NT * CAP];
    __shared__ int cnt_lds[NT];

    int s = blockIdx.x & 7, tb = blockIdx.x >> 3;
    int g = s >> 1;
    int tile = (s & 1) * NTILE + tb;
    int base = tile * NT;
    long gn0 = (long)g * NN;

    if (threadIdx.x < NT) cnt_lds[threadIdx.x] = 0;
    for (int i = threadIdx.x; i < DD * DD; i += blockDim.x) {
        sWl[i] = Wl[(long)g * DD * DD + i];
        sWr[i] = Wr[(long)g * DD * DD + i];
    }
    if (threadIdx.x < DD) sb[threadIdx.x] = bias[g * DD + threadIdx.x];
    __syncthreads();

    int rc = bcnt[(g * NTG + tile) * CPAD];
    int rcount = rc < RCAP ? rc : RCAP;
    const unsigned int* reg = part + (long)(g * NTG + tile) * RCAP;
    for (int i = threadIdx.x; i < rcount; i += 256) {
        unsigned int p = reg[i];
        int dl = (p >> 16) & 63;
        int pos = atomicAdd(&cnt_lds[dl], 1);
        if (pos < CAP) bk[dl * CAP + pos] = (unsigned short)(p & 0xffffu);
    }
    __syncthreads();

    int lane = threadIdx.x & 63;
    int w = threadIdx.x >> 6;
    for (int j = 0; j < 16; ++j) {
        int rl = w * 16 + j;
        int node = base + rl;
        if (node >= NN) continue;
        long row = gn0 + node;
        int ne = cnt_lds[rl];
        int nuse = ne < CAP ? ne : CAP;
        int msrc = (int)bk[rl * CAP + lane];
        float sum = 0.f;
        for (int e = 0; e < nuse; ++e) {
            int a0 = __shfl(msrc, e);
            sum += b2f(xin[(gn0 + a0) * DD + lane]);
        }
        float mean = sum / fmaxf((float)ne, 1.f);
        float self = b2f(xin[row * DD + lane]);
        float acc = sb[lane];
#pragma unroll
        for (int k = 0; k < DD; ++k) {
            float mk = __shfl(mean, k);
            float xk = __shfl(self, k);
            acc += mk * sWl[k * DD + lane] + xk * sWr[k * DD + lane];
        }
        acc = acc > 0.f ? acc : expm1f(acc);
        if (LAYER == 0) ((unsigned short*)outp)[row * DD + lane] = f2b(acc);
        else            ((float*)outp)[row * DD + lane] = acc;
    }
}

extern "C" void kernel_launch(void* const* d_in, const int* in_sizes, int n_in,
                              void* d_out, int out_size, void* d_ws, size_t ws_size,
                              hipStream_t stream) {
    const float* x   = (const float*)d_in[0];
    const int*   ei  = (const int*)d_in[1];
    const float* Wl1 = (const float*)d_in[2];
    const float* Wr1 = (const float*)d_in[3];
    const float* b1  = (const float*)d_in[4];
    const float* Wl2 = (const float*)d_in[5];
    const float* Wr2 = (const float*)d_in[6];
    const float* b2  = (const float*)d_in[7];
    float* out = (float*)d_out;

    // ws: part u32[4*782*1536] (19.2MB) | bcnt i32[4*782*16 padded] (200KB) |
    //     h u16[4*50000*64] (25.6MB) | flags i32  -> ~45.0MB < 52MB proven
    unsigned int* part = (unsigned int*)d_ws;
    int* bcnt = (int*)(part + (size_t)NG * NTG * RCAP);
    unsigned short* h = (unsigned short*)(bcnt + (size_t)NG * NTG * CPAD);
    int* flags = (int*)(h + (size_t)NG * NN * DD);
    // xb (x as bf16, 25.6MB) lives in d_out's first half; dead before layer 2
    unsigned short* xb = (unsigned short*)d_out;

    hipMemsetAsync(bcnt, 0, (size_t)NG * NTG * CPAD * sizeof(int), stream);
    init_kernel<<<1, 64, 0, stream>>>(ei, flags);
    partition_kernel<<<2048, 256, 0, stream>>>(ei, flags, bcnt, part);
    convert_kernel<<<2048, 256, 0, stream>>>(x, xb);

    const int grid = NTILE * 8;  // 391 tb x 8 XCD slots
    // layer 1: xb -> h (bf16)
    sage_mfma_kernel<0><<<grid, 256, 0, stream>>>(xb, bcnt, part, Wl1, Wr1, b1, h, flags);
    fallback_kernel<0><<<grid, 256, 0, stream>>>(xb, bcnt, part, Wl1, Wr1, b1, h, flags);
    // layer 2: h -> out (f32)
    sage_mfma_kernel<1><<<grid, 256, 0, stream>>>(h, bcnt, part, Wl2, Wr2, b2, out, flags);
    fallback_kernel<1><<<grid, 256, 0, stream>>>(h, bcnt, part, Wl2, Wr2, b2, out, flags);
}

// Round 10
// 302.517 us; speedup vs baseline: 2.0546x; 1.3227x over previous
//
#include <hip/hip_runtime.h>
#include <hip/hip_bf16.h>
#include <math.h>

#define NG 4
#define NN 50000
#define NE 800000
#define DD 64
#define CAP 64
#define NT 64             // nodes per block tile
#define NTILE 391         // tiles per (graph, half)
#define NTG (2 * NTILE)   // tiles (regions) per graph = 782
#define RCAP 1536         // region capacity (Poisson mean 1024, 16 sigma)
#define CPAD 16           // ints per region counter (one 64B line each)
#define PBLK 128          // partition blocks per slot (1024 total)
#define CHUNK (NE / PBLK) // 6250 edges per block
#define LBINS 392         // regions a slot can touch (half spans 391-392 tiles)
#define BCAP 20           // LDS bin capacity (Poisson mean 8; P(>=20)~1e-4 -> overflow path)

typedef __attribute__((ext_vector_type(8))) short short8;
typedef __attribute__((ext_vector_type(4))) float float4v;

__device__ __forceinline__ unsigned short f2b(float f) {
    union { __hip_bfloat16 h; unsigned short u; } cv;
    cv.h = __float2bfloat16(f);
    return cv.u;
}
__device__ __forceinline__ float b2f(unsigned short u) {
    union { unsigned short u; __hip_bfloat16 h; } cv;
    cv.u = u;
    return __bfloat162float(cv.h);
}

// ---- init: detect int64 (bit0) + verify MFMA layout (bit1), one block ------
__global__ void init_kernel(const int* __restrict__ ei, int* __restrict__ flags) {
    __shared__ alignas(16) unsigned short A[16 * 32];
    __shared__ unsigned short B[32 * 16];
    int t = threadIdx.x;
    int any_nonzero = 0;
    for (int i = t; i < 128; i += 64) any_nonzero |= ei[2 * i + 1];
    unsigned long long nz = __ballot(any_nonzero != 0);
    int is64 = (nz == 0ULL) ? 1 : 0;
    for (int i = t; i < 512; i += 64) {
        int r = i >> 5, k = i & 31;
        A[i] = f2b((float)(((r * 5 + k * 3) & 31) - 15));
        int kk = i >> 4, c = i & 15;
        B[i] = f2b((float)(((kk * 7 + c * 11) & 31) - 15));
    }
    __syncthreads();
    short8 a = *(const short8*)&A[(t & 15) * 32 + (t >> 4) * 8];
    int c = t & 15, kb = (t >> 4) * 8;
    short8 b;
    for (int j = 0; j < 8; ++j) b[j] = (short)B[(kb + j) * 16 + c];
    float4v acc = {0.f, 0.f, 0.f, 0.f};
    acc = __builtin_amdgcn_mfma_f32_16x16x32_bf16(a, b, acc, 0, 0, 0);
    int ok = 1;
    for (int reg = 0; reg < 4; ++reg) {
        int row = (t >> 4) * 4 + reg;
        float ref = 0.f;
        for (int k = 0; k < 32; ++k)
            ref += (float)(((row * 5 + k * 3) & 31) - 15) *
                   (float)(((k * 7 + c * 11) & 31) - 15);
        if (acc[reg] != ref) ok = 0;
    }
    unsigned long long vote = __ballot(ok);
    if (t == 0) flags[0] = is64 | ((vote == ~0ULL) ? 2 : 0);
}

// nt (streaming) edge-index load
__device__ __forceinline__ int nt_idx(const int* __restrict__ ei, long pos, int is64) {
    return is64 ? __builtin_nontemporal_load(ei + 2 * pos)
                : __builtin_nontemporal_load(ei + pos);
}

// ---- partition via LDS-staged aggregation ----------------------------------
// ROUND-10 CHANGE: rounds 8/9 showed device-scope atomics bypass L2 (XCD L2s
// non-coherent) -> each of 3.2M atomicAdds = ~32B EA transaction (121MB
// WRITE_SIZE, ~1TB/s ceiling, 150us). Fix: bin each block's contiguous
// 6250-edge chunk into LDS (LDS atomics, on-CU), then flush with ONE global
// atomicAdd per (block,region) reservation (~400K total, 8x fewer) + burst
// copy of ~8 consecutive u32 per region. Overflow paths keep correctness.
__global__ void partition_kernel(const int* __restrict__ ei, const int* __restrict__ flags,
                                 int* __restrict__ bcnt, unsigned int* __restrict__ part) {
    __shared__ int lcnt[LBINS];
    __shared__ int basev[LBINS];
    __shared__ unsigned int lbuf[LBINS * BCAP];   // 31.4KB

    int is64 = flags[0] & 1;
    int s = blockIdx.x & 7;          // -> XCD s (round-robin dispatch heuristic)
    int g = s >> 1;
    int lo = (s & 1) * (NN / 2), hi = lo + (NN / 2);
    int rbase0 = lo >> 6;            // first region this slot touches
    int bsl = blockIdx.x >> 3;       // 0..PBLK-1
    int e0 = bsl * CHUNK, e1 = e0 + CHUNK;
    long ebase = (long)g * 2 * NE;

    for (int i = threadIdx.x; i < LBINS; i += 256) lcnt[i] = 0;
    __syncthreads();

    // bin chunk into LDS
    for (int e = e0 + threadIdx.x; e < e1; e += 256) {
        int d = nt_idx(ei, ebase + NE + e, is64);
        int sc = nt_idx(ei, ebase + e, is64);
        if (d >= lo && d < hi) {
            int lb = (d >> 6) - rbase0;
            unsigned int pk = ((unsigned int)d << 16) | (unsigned int)(sc & 0xffff);
            int pos = atomicAdd(&lcnt[lb], 1);
            if (pos < BCAP) {
                lbuf[lb * BCAP + pos] = pk;
            } else {  // rare overflow: direct global append
                int gp = atomicAdd(&bcnt[(g * NTG + (d >> 6)) * CPAD], 1);
                if (gp < RCAP) part[(long)(g * NTG + (d >> 6)) * RCAP + gp] = pk;
            }
        }
    }
    __syncthreads();

    // reserve: one global atomic per non-empty (block, region), all parallel
    for (int r = threadIdx.x; r < LBINS; r += 256) {
        int c = lcnt[r]; c = c < BCAP ? c : BCAP;
        basev[r] = c ? atomicAdd(&bcnt[(g * NTG + rbase0 + r) * CPAD], c) : 0;
    }
    __syncthreads();

    // burst copy: half-wave per region
    int w = threadIdx.x >> 6, hw = (threadIdx.x >> 5) & 1, l32 = threadIdx.x & 31;
    for (int r = w * 2 + hw; r < LBINS; r += 8) {
        int c = lcnt[r]; c = c < BCAP ? c : BCAP;
        int b = basev[r];
        if (l32 < c && b + l32 < RCAP)
            part[(long)(g * NTG + rbase0 + r) * RCAP + b + l32] = lbuf[r * BCAP + l32];
    }
}

// ---- convert x f32 -> bf16 -------------------------------------------------
__global__ void convert_kernel(const float* __restrict__ x, unsigned short* __restrict__ xb) {
    long total = (long)NG * NN * DD / 4;
    long stride = (long)gridDim.x * blockDim.x;
    const float4* src = (const float4*)x;
    unsigned long long* dst = (unsigned long long*)xb;
    for (long i = (long)blockIdx.x * blockDim.x + threadIdx.x; i < total; i += stride) {
        float4 v = src[i];
        unsigned long long p = (unsigned long long)f2b(v.x)
                             | ((unsigned long long)f2b(v.y) << 16)
                             | ((unsigned long long)f2b(v.z) << 32)
                             | ((unsigned long long)f2b(v.w) << 48);
        dst[i] = p;
    }
}

// ---- fused bin + gather + MFMA layer (unchanged from rounds 8/9) ------------
template <int LAYER>  // 0: out = h (bf16), 1: out = d_out (f32)
__launch_bounds__(256, 6)
__global__ void sage_mfma_kernel(const unsigned short* __restrict__ xin,
                                 const int* __restrict__ bcnt,
                                 const unsigned int* __restrict__ part,
                                 const float* __restrict__ Wl, const float* __restrict__ Wr,
                                 const float* __restrict__ bias, void* __restrict__ outp,
                                 const int* __restrict__ flags) {
    if (!(flags[0] & 2)) return;
    __shared__ alignas(16) unsigned short sWT[2 * DD * DD];  // [m][col][k^swz] bf16, 16KB
    __shared__ alignas(16) unsigned short sM[NT * DD];       // bucket, then means, 8KB
    __shared__ int cnt_lds[NT];

    int s = blockIdx.x & 7, tb = blockIdx.x >> 3;
    int g = s >> 1;
    int tile = (s & 1) * NTILE + tb;
    int base = tile * NT;
    long gn0 = (long)g * NN;

    if (threadIdx.x < NT) cnt_lds[threadIdx.x] = 0;

    for (int i = threadIdx.x; i < 1024; i += 256) {
        int col = i & 63, ko = (i >> 6) & 7, m = i >> 9;
        const float* Wsrc = (m == 0 ? Wl : Wr) + (long)g * DD * DD;
        short8 t;
#pragma unroll
        for (int j = 0; j < 8; ++j)
            t[j] = (short)f2b(Wsrc[(ko * 8 + j) * DD + col]);
        *(short8*)&sWT[m * DD * DD + col * DD + ((ko * 8) ^ ((col & 7) << 3))] = t;
    }
    __syncthreads();

    // ---- bin this tile's region into LDS ----
    int rc = bcnt[(g * NTG + tile) * CPAD];
    int rcount = rc < RCAP ? rc : RCAP;
    const unsigned int* reg = part + (long)(g * NTG + tile) * RCAP;
    for (int i = threadIdx.x; i < rcount; i += 256) {
        unsigned int p = reg[i];
        int dl = (p >> 16) & 63;
        int pos = atomicAdd(&cnt_lds[dl], 1);
        if (pos < CAP) sM[dl * DD + pos] = (unsigned short)(p & 0xffffu);
    }
    __syncthreads();

    int lane = threadIdx.x & 63;
    int w = threadIdx.x >> 6;

    // ---- gather phase: bf16 means for this wave's 16 rows ----
#pragma unroll 1
    for (int j = 0; j < 16; ++j) {
        int rl = w * 16 + j;
        int node = base + rl;
        int ne = cnt_lds[rl];
        int nuse = ne < CAP ? ne : CAP;
        int msrc = (int)sM[rl * DD + lane];   // bucket row (dead after this j)
        float mean = 0.f;
        if (node < NN) {
            float s0 = 0.f, s1 = 0.f, s2 = 0.f, s3 = 0.f;
            int e = 0;
            for (; e + 4 <= nuse; e += 4) {
                int a0 = __shfl(msrc, e), a1 = __shfl(msrc, e + 1);
                int a2 = __shfl(msrc, e + 2), a3 = __shfl(msrc, e + 3);
                s0 += b2f(xin[(gn0 + a0) * DD + lane]);
                s1 += b2f(xin[(gn0 + a1) * DD + lane]);
                s2 += b2f(xin[(gn0 + a2) * DD + lane]);
                s3 += b2f(xin[(gn0 + a3) * DD + lane]);
            }
            if (e < nuse) {
                int r = nuse - e;
                int a0 = __shfl(msrc, e);
                int a1 = __shfl(msrc, r > 1 ? e + 1 : e);
                int a2 = __shfl(msrc, r > 2 ? e + 2 : e);
                float v0 = b2f(xin[(gn0 + a0) * DD + lane]);
                float v1 = b2f(xin[(gn0 + a1) * DD + lane]);
                float v2 = b2f(xin[(gn0 + a2) * DD + lane]);
                s0 += v0;
                if (r > 1) s1 += v1;
                if (r > 2) s2 += v2;
            }
            mean = ((s0 + s1) + (s2 + s3)) / fmaxf((float)ne, 1.f);
        }
        sM[rl * DD + (lane ^ ((rl & 7) << 3))] = f2b(mean);
    }

    // ---- MFMA phase ----
    int arow = w * 16 + (lane & 15);
    int kb = (lane >> 4) * 8;
    int selfrow = base + arow; if (selfrow > NN - 1) selfrow = NN - 1;
    short8 am[2], ax[2];
#pragma unroll
    for (int ss = 0; ss < 2; ++ss) {
        int f0 = (kb + 32 * ss) ^ ((arow & 7) << 3);
        am[ss] = *(const short8*)&sM[arow * DD + f0];
        ax[ss] = *(const short8*)&xin[(gn0 + selfrow) * DD + kb + 32 * ss];
    }

    float4v acc[4];
#pragma unroll
    for (int c = 0; c < 4; ++c) {
        float b = bias[g * DD + c * 16 + (lane & 15)];
        acc[c] = {b, b, b, b};
    }
#pragma unroll
    for (int c = 0; c < 4; ++c) {
        int col = c * 16 + (lane & 15);
        int cswz = (col & 7) << 3;
#pragma unroll
        for (int ss = 0; ss < 2; ++ss) {
            short8 bl = *(const short8*)&sWT[0 * DD * DD + col * DD + ((kb + 32 * ss) ^ cswz)];
            acc[c] = __builtin_amdgcn_mfma_f32_16x16x32_bf16(am[ss], bl, acc[c], 0, 0, 0);
        }
#pragma unroll
        for (int ss = 0; ss < 2; ++ss) {
            short8 br = *(const short8*)&sWT[1 * DD * DD + col * DD + ((kb + 32 * ss) ^ cswz)];
            acc[c] = __builtin_amdgcn_mfma_f32_16x16x32_bf16(ax[ss], br, acc[c], 0, 0, 0);
        }
    }

    int q = lane >> 4, cl = lane & 15;
#pragma unroll
    for (int c = 0; c < 4; ++c) {
        int col = c * 16 + cl;
#pragma unroll
        for (int r = 0; r < 4; ++r) {
            int grow = base + w * 16 + q * 4 + r;
            if (grow >= NN) continue;
            float v = acc[c][r];
            v = v > 0.f ? v : expm1f(v);
            if (LAYER == 0)
                ((unsigned short*)outp)[(gn0 + grow) * DD + col] = f2b(v);
            else
                ((float*)outp)[(gn0 + grow) * DD + col] = v;
        }
    }
}

// ---- fallback (shfl-matvec on binned tile), runs only if probe failed ------
template <int LAYER>
__global__ void fallback_kernel(const unsigned short* __restrict__ xin,
                                const int* __restrict__ bcnt,
                                const unsigned int* __restrict__ part,
                                const float* __restrict__ Wl, const float* __restrict__ Wr,
                                const float* __restrict__ bias, void* __restrict__ outp,
                                const int* __restrict__ flags) {
    if (flags[0] & 2) return;
    __shared__ float sWl[DD * DD];
    __shared__ float sWr[DD * DD];
    __shared__ float sb[DD];
    __shared__ unsigned short bk[NT * CAP];
    __shared__ int cnt_lds[NT];

    int s = blockIdx.x & 7, tb = blockIdx.x >> 3;
    int g = s >> 1;
    int tile = (s & 1) * NTILE + tb;
    int base = tile * NT;
    long gn0 = (long)g * NN;

    if (threadIdx.x < NT) cnt_lds[threadIdx.x] = 0;
    for (int i = threadIdx.x; i < DD * DD; i += blockDim.x) {
        sWl[i] = Wl[(long)g * DD * DD + i];
        sWr[i] = Wr[(long)g * DD * DD + i];
    }
    if (threadIdx.x < DD) sb[threadIdx.x] = bias[g * DD + threadIdx.x];
    __syncthreads();

    int rc = bcnt[(g * NTG + tile) * CPAD];
    int rcount = rc < RCAP ? rc : RCAP;
    const unsigned int* reg = part + (long)(g * NTG + tile) * RCAP;
    for (int i = threadIdx.x; i < rcount; i += 256) {
        unsigned int p = reg[i];
        int dl = (p >> 16) & 63;
        int pos = atomicAdd(&cnt_lds[dl], 1);
        if (pos < CAP) bk[dl * CAP + pos] = (unsigned short)(p & 0xffffu);
    }
    __syncthreads();

    int lane = threadIdx.x & 63;
    int w = threadIdx.x >> 6;
    for (int j = 0; j < 16; ++j) {
        int rl = w * 16 + j;
        int node = base + rl;
        if (node >= NN) continue;
        long row = gn0 + node;
        int ne = cnt_lds[rl];
        int nuse = ne < CAP ? ne : CAP;
        int msrc = (int)bk[rl * CAP + lane];
        float sum = 0.f;
        for (int e = 0; e < nuse; ++e) {
            int a0 = __shfl(msrc, e);
            sum += b2f(xin[(gn0 + a0) * DD + lane]);
        }
        float mean = sum / fmaxf((float)ne, 1.f);
        float self = b2f(xin[row * DD + lane]);
        float acc = sb[lane];
#pragma unroll
        for (int k = 0; k < DD; ++k) {
            float mk = __shfl(mean, k);
            float xk = __shfl(self, k);
            acc += mk * sWl[k * DD + lane] + xk * sWr[k * DD + lane];
        }
        acc = acc > 0.f ? acc : expm1f(acc);
        if (LAYER == 0) ((unsigned short*)outp)[row * DD + lane] = f2b(acc);
        else            ((float*)outp)[row * DD + lane] = acc;
    }
}

extern "C" void kernel_launch(void* const* d_in, const int* in_sizes, int n_in,
                              void* d_out, int out_size, void* d_ws, size_t ws_size,
                              hipStream_t stream) {
    const float* x   = (const float*)d_in[0];
    const int*   ei  = (const int*)d_in[1];
    const float* Wl1 = (const float*)d_in[2];
    const float* Wr1 = (const float*)d_in[3];
    const float* b1  = (const float*)d_in[4];
    const float* Wl2 = (const float*)d_in[5];
    const float* Wr2 = (const float*)d_in[6];
    const float* b2  = (const float*)d_in[7];
    float* out = (float*)d_out;

    // ws: part u32[4*782*1536] (19.2MB) | bcnt i32[4*782*16 padded] (200KB) |
    //     h u16[4*50000*64] (25.6MB) | flags i32  -> ~45.0MB < 52MB proven
    unsigned int* part = (unsigned int*)d_ws;
    int* bcnt = (int*)(part + (size_t)NG * NTG * RCAP);
    unsigned short* h = (unsigned short*)(bcnt + (size_t)NG * NTG * CPAD);
    int* flags = (int*)(h + (size_t)NG * NN * DD);
    // xb (x as bf16, 25.6MB) lives in d_out's first half; dead before layer 2
    unsigned short* xb = (unsigned short*)d_out;

    hipMemsetAsync(bcnt, 0, (size_t)NG * NTG * CPAD * sizeof(int), stream);
    init_kernel<<<1, 64, 0, stream>>>(ei, flags);
    partition_kernel<<<PBLK * 8, 256, 0, stream>>>(ei, flags, bcnt, part);
    convert_kernel<<<2048, 256, 0, stream>>>(x, xb);

    const int grid = NTILE * 8;  // 391 tb x 8 XCD slots
    // layer 1: xb -> h (bf16)
    sage_mfma_kernel<0><<<grid, 256, 0, stream>>>(xb, bcnt, part, Wl1, Wr1, b1, h, flags);
    fallback_kernel<0><<<grid, 256, 0, stream>>>(xb, bcnt, part, Wl1, Wr1, b1, h, flags);
    // layer 2: h -> out (f32)
    sage_mfma_kernel<1><<<grid, 256, 0, stream>>>(h, bcnt, part, Wl2, Wr2, b2, out, flags);
    fallback_kernel<1><<<grid, 256, 0, stream>>>(h, bcnt, part, Wl2, Wr2, b2, out, flags);
}